// Round 7
// baseline (125.376 us; speedup 1.0000x reference)
//
#include <hip/hip_runtime.h>

#define BB 4
#define NN 1024
#define KK 9
#define C  32
#define CM 128
#define M  (BB*NN)       // 4096 rows
#define EPSB 1e-5f
#define SLOPE 0.01f

#define KPAD 296         // kmt row stride (f16): 288 + 8 (16B aligned)
#define WTS  40          // wT row stride (f16): 32 + 8 (16B aligned)
#define GAP  296         // gA / cwB row stride (f16), 592 B = 37*16
#define HPAD 136         // K5 hA/w2B row stride (f16), 272 B = 17*16

typedef _Float16 f16x8 __attribute__((ext_vector_type(8)));
typedef _Float16 f16x4 __attribute__((ext_vector_type(4)));
typedef float    f32x4 __attribute__((ext_vector_type(4)));

__device__ __forceinline__ float leaky(float x){ return x > 0.f ? x : SLOPE*x; }

__device__ __forceinline__ float fexp2(float x){
#if __has_builtin(__builtin_amdgcn_exp2f)
  return __builtin_amdgcn_exp2f(x);
#else
  return exp2f(x);
#endif
}

// ---------------------------------------------------------------------------
// K2: g[i,k,c'] = sum_n km[i,n,k]*w[n,c'] (MFMA main loop), then epilogue
// y = g @ conv_w as a second MFMA (hi/lo f16 split, ~f32-exact).
// R6 deltas vs R5: (a) GEN position reads via 2x ds_read_b128 instead of
// 8x b32; (b) conv_w prefetched into registers BEFORE the main loop (retires
// under the loop; epilogue is pure cvt+ds_write, no exposed global latency).
// Grid 256 = (b, it); 512 thr (8 waves: c'-half = wid&1, q = wid>>1 ->
// k subset {q, q+4, q+8<9}).
// ---------------------------------------------------------------------------
__global__ __launch_bounds__(512) void k2_main(const float* __restrict__ pos,
                                               const float* __restrict__ wts,
                                               const float* __restrict__ kpos,
                                               const float* __restrict__ conv_w,
                                               float* __restrict__ z,
                                               float* __restrict__ zpart,
                                               float* __restrict__ stats){
  __shared__ __align__(16) char smem[67200];
  // main loop layout:
  _Float16* wT0 = (_Float16*)smem;              // [2][32*WTS] f16: 5120 B
  float*    pnl = (float*)(smem + 5120);        // 2048 f32: 8192 B -> 13312
  _Float16* km0 = (_Float16*)(smem + 13312);    // [2][16*KPAD]: 18944 -> 32256
  // epilogue overlays (main-loop buffers dead after final loop barrier):
  _Float16* gAh = (_Float16*)smem;              // [16][GAP] 9472
  _Float16* gAl = (_Float16*)(smem + 9472);     // 9472  -> 18944
  _Float16* cwBh = (_Float16*)(smem + 18944);   // [32][GAP] 18944 -> 37888
  _Float16* cwBl = (_Float16*)(smem + 37888);   // 18944 -> 56832
  float* red  = (float*)(smem + 56832);         // 8*256 f32 -> 65024
  float* red2 = (float*)(smem + 65024);         // 544 f32 -> 67200

  int bid = blockIdx.x;
  int b = bid >> 6, it = bid & 63;
  int tid = threadIdx.x;
  int lane = tid & 63, wid = tid >> 6;
  int mm = lane & 15, quad = lane >> 4;
  int c0 = (wid & 1) * 16, q = wid >> 1;
  int gk = tid >> 7, ig = (tid >> 3) & 15, np = tid & 7;  // GEN role
  int wn = tid >> 4, wc = (tid & 15) * 2;                 // wT-write role

  if (bid == 0){ for (int i = tid; i < 256; i += 512) stats[i] = 0.f; }

  const float BETA = -0.72134752f;  // -0.5 * log2(e)
  float Ak[KK], Bk[KK], Ck[KK];
  #pragma unroll
  for (int k = 0; k < KK; ++k){
    float kxx = kpos[2*k], kyy = kpos[2*k+1];
    Ak[k] = -2.f*BETA*kxx;
    Bk[k] = -2.f*BETA*kyy;
    Ck[k] = BETA*(kxx*kxx + kyy*kyy);
  }

  const float2* wch = (const float2*)(wts + (size_t)b*NN*C);

#define WWRITE(dst, L) do{ \
    (dst)[wc*WTS + wn]     = (_Float16)(L).x; \
    (dst)[(wc+1)*WTS + wn] = (_Float16)(L).y; \
  }while(0)

  // GEN: thread (gk,ig,np) computes 4 n for k in {gk, gk+4, gk+8<9}.
  // Positions read as 2x float4 (8-lane broadcast, 2-way banks = free).
#define GEN(dst, ss) do{ \
    float4 p01_ = ((const float4*)pnl)[(ss)*16 + np*2]; \
    float4 p23_ = ((const float4*)pnl)[(ss)*16 + np*2 + 1]; \
    float dx_[4], dy_[4], e0_[4]; \
    dx_[0] = pix - p01_.x; dy_[0] = piy - p01_.y; \
    dx_[1] = pix - p01_.z; dy_[1] = piy - p01_.w; \
    dx_[2] = pix - p23_.x; dy_[2] = piy - p23_.y; \
    dx_[3] = pix - p23_.z; dy_[3] = piy - p23_.w; \
    _Pragma("unroll") \
    for (int jj = 0; jj < 4; ++jj) \
      e0_[jj] = BETA*(dx_[jj]*dx_[jj] + dy_[jj]*dy_[jj]); \
    _Pragma("unroll") \
    for (int t_ = 0; t_ < 3; ++t_){ \
      int k_ = gk + t_*4; \
      if (k_ < KK){ \
        f16x4 ev_; \
        _Pragma("unroll") \
        for (int jj = 0; jj < 4; ++jj){ \
          float x_ = (e0_[jj] + Ck[k_]) + dx_[jj]*Ak[k_] + dy_[jj]*Bk[k_]; \
          ev_[jj] = (_Float16)fexp2(x_); \
        } \
        *(f16x4*)&(dst)[ig*KPAD + k_*32 + np*4] = ev_; \
      } \
    } \
  }while(0)

  // prologue: positions + chunk0 -> wT[0], prefetch chunk1, then conv_w regs
  ((float4*)pnl)[tid] = ((const float4*)(pos + (size_t)b*NN*2))[tid];
  float2 L0 = wch[tid];           // chunk 0
  float2 Ln = wch[512 + tid];     // chunk 1 (stays in flight)
  // conv_w -> registers (issued AFTER L0/Ln so in-order vmcnt retire doesn't
  // stall the prologue WWRITE; retires under the main loop)
  float4 cwv[5];
  #pragma unroll
  for (int r = 0; r < 5; ++r){
    int v = tid + r*512;
    if (v < (KK*C*C)/4) cwv[r] = ((const float4*)conv_w)[v];
  }
  WWRITE(wT0, L0);
  __syncthreads();
  float pix = pnl[2*(it*16 + ig)];
  float piy = pnl[2*(it*16 + ig) + 1];
  GEN(km0, 0);
  asm volatile("s_waitcnt lgkmcnt(0)" ::: "memory");
  __builtin_amdgcn_s_barrier();
  __builtin_amdgcn_sched_barrier(0);

  f32x4 acc0 = {0.f,0.f,0.f,0.f}, acc1 = {0.f,0.f,0.f,0.f}, acc2 = {0.f,0.f,0.f,0.f};
  for (int s = 0; s < 32; ++s){
    int cur = s & 1;
    if (s < 31){
      float2 Lw = Ln;                              // chunk s+1
      if (s < 30) Ln = wch[(size_t)(s+2)*512 + tid];
      _Float16* wTn = wT0 + (cur^1)*(32*WTS);
      WWRITE(wTn, Lw);                             // compiler-counted vmcnt wait
      _Float16* kmn = km0 + (cur^1)*(16*KPAD);
      GEN(kmn, s+1);
    }
    const _Float16* kmc = km0 + cur*(16*KPAD);
    const _Float16* wTc = wT0 + cur*(32*WTS);
    f16x8 bf = *(const f16x8*)&wTc[(c0+mm)*WTS + quad*8];
    f16x8 a0 = *(const f16x8*)&kmc[mm*KPAD + (q+0)*32 + quad*8];
    acc0 = __builtin_amdgcn_mfma_f32_16x16x32_f16(a0, bf, acc0, 0, 0, 0);
    f16x8 a1 = *(const f16x8*)&kmc[mm*KPAD + (q+4)*32 + quad*8];
    acc1 = __builtin_amdgcn_mfma_f32_16x16x32_f16(a1, bf, acc1, 0, 0, 0);
    if (q == 0){                                   // k=8, wave-uniform
      f16x8 a2 = *(const f16x8*)&kmc[mm*KPAD + 8*32 + quad*8];
      acc2 = __builtin_amdgcn_mfma_f32_16x16x32_f16(a2, bf, acc2, 0, 0, 0);
    }
    asm volatile("s_waitcnt lgkmcnt(0)" ::: "memory");
    __builtin_amdgcn_sched_barrier(0);
    __builtin_amdgcn_s_barrier();
    __builtin_amdgcn_sched_barrier(0);
  }
#undef WWRITE
#undef GEN

  // ---- epilogue: y = g @ conv_w via hi/lo f16 MFMA ----
  // write g (acc regs, C-layout) -> gA hi/lo in A-fragment layout [i][k*32+c']
  #pragma unroll
  for (int r = 0; r < 4; ++r){
    int row = quad*4 + r;
    float v0 = acc0[r];
    _Float16 h0 = (_Float16)v0;
    gAh[row*GAP + (q+0)*32 + c0+mm] = h0;
    gAl[row*GAP + (q+0)*32 + c0+mm] = (_Float16)(v0 - (float)h0);
    float v1 = acc1[r];
    _Float16 h1 = (_Float16)v1;
    gAh[row*GAP + (q+4)*32 + c0+mm] = h1;
    gAl[row*GAP + (q+4)*32 + c0+mm] = (_Float16)(v1 - (float)h1);
    if (q == 0){
      float v2 = acc2[r];
      _Float16 h2 = (_Float16)v2;
      gAh[row*GAP + 8*32 + c0+mm] = h2;
      gAl[row*GAP + 8*32 + c0+mm] = (_Float16)(v2 - (float)h2);
    }
  }
  // stage conv_w[k][c'][c] from REGISTERS -> cwB[c][k*32+c'] hi/lo
  #pragma unroll
  for (int r = 0; r < 5; ++r){
    int v = tid + r*512;
    if (v < (KK*C*C)/4){
      float4 cv = cwv[r];
      int f = v*4;
      int k  = f >> 10;
      int cp = (f >> 5) & 31;
      int cb = f & 31;
      #pragma unroll
      for (int j = 0; j < 4; ++j){
        float x = (&cv.x)[j];
        _Float16 hi = (_Float16)x;
        int c = cb + j;
        cwBh[c*GAP + k*32 + cp] = hi;
        cwBl[c*GAP + k*32 + cp] = (_Float16)(x - (float)hi);
      }
    }
  }
  __syncthreads();

  // wave (c-half = wid&1, q): partial y tile over its k-slices
  f32x4 yacc = {0.f,0.f,0.f,0.f};
  #pragma unroll
  for (int t = 0; t < 3; ++t){
    int ks = q + t*4;
    if (ks < KK){                                  // wave-uniform
      f16x8 ah = *(const f16x8*)&gAh[mm*GAP + ks*32 + quad*8];
      f16x8 al = *(const f16x8*)&gAl[mm*GAP + ks*32 + quad*8];
      f16x8 bh = *(const f16x8*)&cwBh[(c0+mm)*GAP + ks*32 + quad*8];
      f16x8 bl = *(const f16x8*)&cwBl[(c0+mm)*GAP + ks*32 + quad*8];
      yacc = __builtin_amdgcn_mfma_f32_16x16x32_f16(ah, bh, yacc, 0, 0, 0);
      yacc = __builtin_amdgcn_mfma_f32_16x16x32_f16(al, bh, yacc, 0, 0, 0);
      yacc = __builtin_amdgcn_mfma_f32_16x16x32_f16(ah, bl, yacc, 0, 0, 0);
    }
  }
  #pragma unroll
  for (int r = 0; r < 4; ++r) red[wid*256 + (quad*4+r)*16 + mm] = yacc[r];
  __syncthreads();
  {
    int rr = tid >> 5, cc = tid & 31;
    int half = cc >> 4, c15 = cc & 15;
    int o = rr*16 + c15;
    float yv = red[(0+half)*256 + o] + red[(2+half)*256 + o]
             + red[(4+half)*256 + o] + red[(6+half)*256 + o];
    yv = leaky(yv);
    z[((size_t)b*NN + it*16 + rr)*C + cc] = yv;    // 512 consecutive floats
    red2[cc*17 + rr] = yv;
  }
  __syncthreads();
  if (tid < C){
    float s1 = 0.f, s2 = 0.f;
    #pragma unroll
    for (int r = 0; r < 16; ++r){ float t = red2[tid*17 + r]; s1 += t; s2 += t*t; }
    zpart[tid*256 + bid]          = s1;
    zpart[32*256 + tid*256 + bid] = s2;
  }
}

// ---------------------------------------------------------------------------
// K4: zpart reduce -> z-BN; y = bn(z)+weights ; h = leaky(y@w1+b1) via
// hi/lo f16 MFMA (K=32 -> 1 K-step/tile); h-stats atomics into stats[0..255].
// h passed to K5 as packed hi/lo f16x4 in MFMA-C order (coalesced b64).
// Grid 256 (16 rows/block), 256 thr (4 waves; wave -> col-tiles wid*2+{0,1}).
// ---------------------------------------------------------------------------
__global__ __launch_bounds__(256) void k4_mlp1(const float* __restrict__ z,
                                               const float* __restrict__ weights,
                                               const float* __restrict__ bn_g,
                                               const float* __restrict__ bn_b,
                                               const float* __restrict__ w1,
                                               const float* __restrict__ b1,
                                               const float* __restrict__ zpart,
                                               float* __restrict__ stats,
                                               float* __restrict__ y,
                                               _Float16* __restrict__ hhl){
  __shared__ __align__(16) _Float16 yAh[16*WTS], yAl[16*WTS];       // 1280 B each
  __shared__ __align__(16) _Float16 w1Bh[CM*WTS], w1Bl[CM*WTS];     // 10240 B each
  __shared__ float lt1[CM], lt2[CM], b1l[CM];
  __shared__ float zs[2][8][32];
  __shared__ float zf[2][32];
  int tid = threadIdx.x;
  int lane = tid & 63, wid = tid >> 6, mm = lane & 15, quad = lane >> 4;
  int row0 = blockIdx.x * 16;

  {
    int c = tid & 31, seg = tid >> 5;
    const float4* p1 = (const float4*)&zpart[c*256 + seg*32];
    const float4* p2 = (const float4*)&zpart[8192 + c*256 + seg*32];
    float s1 = 0.f, s2 = 0.f;
    #pragma unroll
    for (int j = 0; j < 8; ++j){
      float4 a = p1[j]; s1 += (a.x+a.y)+(a.z+a.w);
      float4 d = p2[j]; s2 += (d.x+d.y)+(d.z+d.w);
    }
    zs[0][seg][c] = s1; zs[1][seg][c] = s2;
  }
  if (tid < CM){ lt1[tid]=0.f; lt2[tid]=0.f; }
  if (tid >= 128) b1l[tid-128] = b1[tid-128];
  __syncthreads();
  if (tid < 64){
    int st = tid >> 5, c = tid & 31;
    float s = 0.f;
    #pragma unroll
    for (int g = 0; g < 8; ++g) s += zs[st][g][c];
    zf[st][c] = s;
  }
  __syncthreads();

  // y = bn(z) + weights; stage as hi/lo A-fragments
  #pragma unroll
  for (int e = tid; e < 512; e += 256){
    int c = e & 31, rl = e >> 5;
    float mean = zf[0][c] * (1.f/M);
    float var  = zf[1][c] * (1.f/M) - mean*mean;
    float sc = bn_g[c] * rsqrtf(var + EPSB);
    float sh = bn_b[c] - mean*sc;
    int row = row0 + rl;
    float v = z[(size_t)row*C + c]*sc + sh + weights[(size_t)row*C + c];
    y[(size_t)row*C + c] = v;
    _Float16 hi = (_Float16)v;
    yAh[rl*WTS + c] = hi;
    yAl[rl*WTS + c] = (_Float16)(v - (float)hi);
  }
  // stage w1[c][col] -> w1B[col][c] hi/lo (B-fragment layout)
  for (int v = tid; v < (C*CM)/4; v += 256){   // 1024 float4
    float4 t = ((const float4*)w1)[v];
    int c = v >> 5, col = (v & 31)*4;
    #pragma unroll
    for (int j = 0; j < 4; ++j){
      float x = (&t.x)[j];
      _Float16 hi = (_Float16)x;
      w1Bh[(col+j)*WTS + c] = hi;
      w1Bl[(col+j)*WTS + c] = (_Float16)(x - (float)hi);
    }
  }
  __syncthreads();

  f16x8 ah = *(const f16x8*)&yAh[mm*WTS + quad*8];
  f16x8 al = *(const f16x8*)&yAl[mm*WTS + quad*8];
  #pragma unroll
  for (int t2 = 0; t2 < 2; ++t2){
    int ct = wid*2 + t2;
    f16x8 bh = *(const f16x8*)&w1Bh[(ct*16+mm)*WTS + quad*8];
    f16x8 bl = *(const f16x8*)&w1Bl[(ct*16+mm)*WTS + quad*8];
    f32x4 acc = {0.f,0.f,0.f,0.f};
    acc = __builtin_amdgcn_mfma_f32_16x16x32_f16(ah, bh, acc, 0, 0, 0);
    acc = __builtin_amdgcn_mfma_f32_16x16x32_f16(al, bh, acc, 0, 0, 0);
    acc = __builtin_amdgcn_mfma_f32_16x16x32_f16(ah, bl, acc, 0, 0, 0);
    float bias = b1l[ct*16+mm];
    float la1 = 0.f, la2 = 0.f;
    f16x4 phi, plo;
    #pragma unroll
    for (int r = 0; r < 4; ++r){
      float v = leaky(acc[r] + bias);
      la1 += v; la2 += v*v;
      _Float16 hi = (_Float16)v;
      phi[r] = hi; plo[r] = (_Float16)(v - (float)hi);
    }
    atomicAdd(&lt1[ct*16+mm], la1);
    atomicAdd(&lt2[ct*16+mm], la2);
    size_t base = ((size_t)(blockIdx.x*256 + tid)*2 + t2)*4;
    *(f16x4*)&hhl[base] = phi;
    *(f16x4*)&hhl[(size_t)M*CM + base] = plo;
  }
  __syncthreads();
  if (tid < CM){
    atomicAdd(&stats[tid],      lt1[tid]);
    atomicAdd(&stats[CM + tid], lt2[tid]);
  }
}

// ---------------------------------------------------------------------------
// K5: out = y + bn1(h)@w2 + b2, with BN1 folded into w2:
//   (h*sc+sh)@w2 = h@(sc⊙w2) + (sh@w2);  bias' = b2 + sh@w2.
// h@w2' via hi/lo f16 MFMA (K=128 -> 4 K-steps, split 2 ways across waves).
// Grid 256 (16 rows/block), 256 thr (4 waves: ct = wid&1, kh = wid>>1).
// ---------------------------------------------------------------------------
__global__ __launch_bounds__(256) void k5_mlp2(const _Float16* __restrict__ hhl,
                                               const float* __restrict__ y,
                                               const float* __restrict__ bn1_g,
                                               const float* __restrict__ bn1_b,
                                               const float* __restrict__ w2,
                                               const float* __restrict__ b2,
                                               const float* __restrict__ stats,
                                               float* __restrict__ out){
  __shared__ __align__(16) _Float16 hAh[16*HPAD], hAl[16*HPAD];     // 4352 B each
  __shared__ __align__(16) _Float16 w2Bh[C*HPAD], w2Bl[C*HPAD];     // 8704 B each
  __shared__ float ssc[CM], ssh[CM];
  __shared__ float bl2[C];
  __shared__ float red[4*256];
  int tid = threadIdx.x;
  int lane = tid & 63, wid = tid >> 6, mm = lane & 15, quad = lane >> 4;
  int row0 = blockIdx.x * 16;

  // h load (mirror of K4's packed store order)
  size_t hb = ((size_t)(blockIdx.x*256 + tid)*2)*4;
  f16x4 h0 = *(const f16x4*)&hhl[hb];
  f16x4 h1 = *(const f16x4*)&hhl[hb + 4];
  f16x4 l0 = *(const f16x4*)&hhl[(size_t)M*CM + hb];
  f16x4 l1 = *(const f16x4*)&hhl[(size_t)M*CM + hb + 4];

  if (tid < CM){
    float t1 = stats[tid], t2 = stats[CM + tid];
    float mean = t1*(1.f/M);
    float var  = t2*(1.f/M) - mean*mean;
    float sc = bn1_g[tid]*rsqrtf(var + EPSB);
    ssc[tid] = sc;
    ssh[tid] = bn1_b[tid] - mean*sc;
  }
  if (tid >= 128 && tid < 160) bl2[tid-128] = b2[tid-128];

  // scatter h into A-fragment layout [row][j]
  #pragma unroll
  for (int t2 = 0; t2 < 2; ++t2){
    int col = (wid*2 + t2)*16 + mm;
    #pragma unroll
    for (int r = 0; r < 4; ++r){
      int row = quad*4 + r;
      hAh[row*HPAD + col] = t2 ? h1[r] : h0[r];
      hAl[row*HPAD + col] = t2 ? l1[r] : l0[r];
    }
  }
  __syncthreads();   // ssc/ssh/bl2 ready

  // stage w2' = sc⊙w2 hi/lo (B-layout [c][j]) + bias' partials
  for (int v = tid; v < (CM*C)/4; v += 256){   // 1024 float4
    float4 t = ((const float4*)w2)[v];
    int j = v >> 3, c4 = (v & 7)*4;
    float scj = ssc[j], shj = ssh[j];
    #pragma unroll
    for (int jj = 0; jj < 4; ++jj){
      float x = (&t.x)[jj];
      int c = c4 + jj;
      atomicAdd(&bl2[c], shj * x);
      float xp = x * scj;
      _Float16 hi = (_Float16)xp;
      w2Bh[c*HPAD + j] = hi;
      w2Bl[c*HPAD + j] = (_Float16)(xp - (float)hi);
    }
  }
  __syncthreads();

  // MFMA: wave (ct = wid&1, kh = wid>>1): K-steps ks = kh*2 + {0,1}
  int ct = wid & 1, kh = wid >> 1;
  f32x4 acc = {0.f,0.f,0.f,0.f};
  #pragma unroll
  for (int ks2 = 0; ks2 < 2; ++ks2){
    int ks = kh*2 + ks2;
    f16x8 ah = *(const f16x8*)&hAh[mm*HPAD + ks*32 + quad*8];
    f16x8 al = *(const f16x8*)&hAl[mm*HPAD + ks*32 + quad*8];
    f16x8 bh = *(const f16x8*)&w2Bh[(ct*16+mm)*HPAD + ks*32 + quad*8];
    f16x8 bl = *(const f16x8*)&w2Bl[(ct*16+mm)*HPAD + ks*32 + quad*8];
    acc = __builtin_amdgcn_mfma_f32_16x16x32_f16(ah, bh, acc, 0, 0, 0);
    acc = __builtin_amdgcn_mfma_f32_16x16x32_f16(al, bh, acc, 0, 0, 0);
    acc = __builtin_amdgcn_mfma_f32_16x16x32_f16(ah, bl, acc, 0, 0, 0);
  }
  #pragma unroll
  for (int r = 0; r < 4; ++r) red[wid*256 + (quad*4+r)*16 + mm] = acc[r];
  __syncthreads();

  #pragma unroll
  for (int e = tid; e < 512; e += 256){
    int rr = e >> 5, cc = e & 31;
    int half = cc >> 4;
    int o = rr*16 + (cc & 15);
    float val = red[half*256 + o] + red[(2+half)*256 + o];
    int row = row0 + rr;
    out[(size_t)row*C + cc] = y[(size_t)row*C + cc] + bl2[cc] + val;
  }
}

// ---------------------------------------------------------------------------
extern "C" void kernel_launch(void* const* d_in, const int* in_sizes, int n_in,
                              void* d_out, int out_size, void* d_ws, size_t ws_size,
                              hipStream_t stream) {
  const float* positions = (const float*)d_in[0];
  const float* weights   = (const float*)d_in[1];
  const float* kpos      = (const float*)d_in[2];
  const float* conv_w    = (const float*)d_in[3];
  const float* bn_g      = (const float*)d_in[4];
  const float* bn_b      = (const float*)d_in[5];
  const float* w1        = (const float*)d_in[6];
  const float* b1        = (const float*)d_in[7];
  const float* bn1_g     = (const float*)d_in[8];
  const float* bn1_b     = (const float*)d_in[9];
  const float* w2        = (const float*)d_in[10];
  const float* b2        = (const float*)d_in[11];
  float* out = (float*)d_out;

  float* ws = (float*)d_ws;
  float* z       = ws;                      // M*C = 131072
  float* y       = ws + 131072;             // M*C = 131072
  _Float16* hhl  = (_Float16*)(ws + 262144);// 2 * M*CM f16 = 524288 f32 slots
  float* zpart   = ws + 786432;             // 2*32*256 = 16384
  float* stats   = ws + 802816;             // 256

  k2_main<<<256, 512, 0, stream>>>(positions, weights, kpos, conv_w, z, zpart, stats);
  k4_mlp1<<<256, 256, 0, stream>>>(z, weights, bn_g, bn_b, w1, b1, zpart, stats, y, hhl);
  k5_mlp2<<<256, 256, 0, stream>>>(hhl, y, bn1_g, bn1_b, w2, b2, stats, out);
}